// Round 11
// baseline (265.731 us; speedup 1.0000x reference)
//
#include <hip/hip_runtime.h>
#include <math.h>

// GCN 4-layer, N=100k, E=3.2M. Round 11:
//  - Finer source-class sort in k_build: 8 -> 32 classes (src>>12, 256KB of
//    Gh per class). Round-10 evidence: (node,class) sort alone cut agg FETCH
//    139->99MB via phase-aligned gathers across resident waves. Zero cost in
//    the aggs; k_build moves to 4096 bins with in-place LDS scan.
//  - cnt8 side output deleted (was never read).
// Identities: norm factorizes (dinv pre/post scale); matmul commutes with
// segment-sum, so layers 1/4 aggregate scalars.

#define BLK 256
#define PBLK 1024         // k_place threads
#define NBLK 256          // edge-pass blocks
#define MAXCHUNK 12544    // >= ceil(E/NBLK)=12500
#define CAP 5120          // per-bucket segment capacity (mean 4096, +16 sigma)

typedef _Float16 half8 __attribute__((ext_vector_type(8)));

// ---- CSR build ----------------------------------------------------------

__global__ void k_initcur(int* __restrict__ cursor, int NB) {
    int b = blockIdx.x * blockDim.x + threadIdx.x;
    if (b < NB) cursor[b] = b * CAP;
}

// per-block LDS multisplit + coalesced flush into segmented bkt regions
__global__ void __launch_bounds__(PBLK) k_place(
        const int* __restrict__ src, const int* __restrict__ dst,
        int* __restrict__ cursor, int* __restrict__ bkt, int E, int chunk) {
    __shared__ int hist[788];          // counts, then wbase after reservation
    __shared__ int lofs[788];
    __shared__ int lcur[788];
    __shared__ int tmp[PBLK];
    __shared__ int stage[MAXCHUNK];
    int t = threadIdx.x;
    int b0 = blockIdx.x * chunk;
    int b1 = min(E, b0 + chunk);
    int n = b1 - b0;
    if (t < 788) hist[t] = 0;
    __syncthreads();
    for (int k = b0 + t; k < b1; k += PBLK) atomicAdd(&hist[dst[k] >> 7], 1);
    __syncthreads();
    int v = (t < 788) ? hist[t] : 0;
    tmp[t] = v;
    __syncthreads();
    for (int o = 1; o < PBLK; o <<= 1) {
        int a = (t >= o) ? tmp[t - o] : 0;
        __syncthreads();
        tmp[t] += a;
        __syncthreads();
    }
    int ex = tmp[t] - v;
    if (t < 788) { lofs[t] = ex; lcur[t] = ex; }
    __syncthreads();
    if (t < 782) {
        int c = hist[t];
        hist[t] = c ? atomicAdd(&cursor[t], c) : 0;   // segmented reservation
    }
    __syncthreads();
    for (int k = b0 + t; k < b1; k += PBLK) {
        int d = dst[k], s = src[k];
        int b = d >> 7;
        int p = atomicAdd(&lcur[b], 1);
        stage[p] = s | ((d & 127) << 17);
    }
    __syncthreads();
    for (int k = t; k < n; k += PBLK) {
        int lo = 0, hi = 781;
        while (lo < hi) {
            int mid = (lo + hi + 1) >> 1;
            if (lofs[mid] <= k) lo = mid; else hi = mid - 1;
        }
        int pos = hist[lo] + (k - lofs[lo]);
        if (pos < (lo + 1) * CAP) bkt[pos] = stage[k];   // clamp (never hits)
    }
}

// block per bucket -> 4096-bin (node, src>>12) hist + in-place scan, LDS
// scatter, linear flush; writes rs2 (beg,len), dinv, sa
__global__ void k_build(const int* __restrict__ cursor, const int* __restrict__ bkt,
                        const float* __restrict__ x,
                        uint2* __restrict__ rs2, int* __restrict__ ss,
                        float* __restrict__ dinv, float* __restrict__ sa, int N) {
    __shared__ int lofs[4096];          // histogram, then exclusive offsets
    __shared__ int lcur[4096];
    __shared__ int tmp[BLK];
    __shared__ int stg[CAP];
    int b = blockIdx.x, t = threadIdx.x;
    int node_base = b << 7;
    int gb = b * CAP;
    int sz = min(cursor[b] - gb, CAP);
    for (int i = t; i < 4096; i += BLK) lofs[i] = 0;
    __syncthreads();
    const int* q = bkt + gb;
    for (int k = t; k < sz; k += BLK) {
        int v = q[k];
        int bin = (((v >> 17) & 127) << 5) | (((v & 0x1FFFF) >> 12) & 31);
        atomicAdd(&lofs[bin], 1);
    }
    __syncthreads();
    // in-place scan of 4096 bins, 16 per thread
    int vals[16];
    int sum = 0;
    int i0 = t << 4;
    #pragma unroll
    for (int r = 0; r < 16; ++r) { vals[r] = lofs[i0 + r]; sum += vals[r]; }
    tmp[t] = sum;
    __syncthreads();
    for (int o = 1; o < BLK; o <<= 1) {
        int a = (t >= o) ? tmp[t - o] : 0;
        __syncthreads();
        tmp[t] += a;
        __syncthreads();
    }
    int run = tmp[t] - sum;
    #pragma unroll
    for (int r = 0; r < 16; ++r) {
        int c = vals[r];
        lofs[i0 + r] = run;
        lcur[i0 + r] = run;
        run += c;
    }
    __syncthreads();
    if (t < 128) {
        int i = node_base + t;
        if (i < N) {
            int beg = lofs[t << 5];
            int end = (t < 127) ? lofs[(t + 1) << 5] : sz;
            int len = end - beg;
            rs2[i] = make_uint2((unsigned)(gb + beg), (unsigned)len);
            float d = rsqrtf((float)len + 1.0f);
            dinv[i] = d;
            sa[i] = x[i] * d;
        }
    }
    __syncthreads();
    for (int k = t; k < sz; k += BLK) {
        int v = q[k];
        int bin = (((v >> 17) & 127) << 5) | (((v & 0x1FFFF) >> 12) & 31);
        int pos = atomicAdd(&lcur[bin], 1);
        stg[pos] = v & 0x1FFFF;
    }
    __syncthreads();
    for (int k = t; k < sz; k += BLK) ss[gb + k] = stg[k];
}

// ---- layers -------------------------------------------------------------

// layer 1 + fused layer-2 matvec: scalar gather -> F1 (lane=feature) ->
// Gh[i,l] = dinv_i * sum_k F1_k * Wmid[k][l], via 32 shuffles
__global__ void k_l1aggG(const uint2* __restrict__ rs2, const int* __restrict__ ss,
                         const float* __restrict__ sa, const float* __restrict__ dinv,
                         const float* __restrict__ Win, const float* __restrict__ bin,
                         const float* __restrict__ Wmid, _Float16* __restrict__ Gh, int N) {
    int t = blockIdx.x * blockDim.x + threadIdx.x;
    int i = t >> 5, l = t & 31;
    if (i >= N) return;
    float wcol[32];
    #pragma unroll
    for (int k = 0; k < 32; ++k) wcol[k] = Wmid[k * 32 + l];
    uint2 r = rs2[i];
    int beg = (int)r.x, end = (int)(r.x + r.y);
    float s = 0.f;
    for (int e = beg + l; e < end; e += 32) s += sa[ss[e]];
    #pragma unroll
    for (int m = 16; m; m >>= 1) s += __shfl_xor(s, m, 32);
    float d = dinv[i];
    float h = d * (s + sa[i]);
    float F = h * Win[l] + bin[l];
    F = F > 0.f ? F : 0.f;
    float g = 0.f;
    #pragma unroll
    for (int k = 0; k < 32; ++k) g += __shfl(F, k, 32) * wcol[k];
    Gh[t] = (_Float16)(g * d);
}

// layer-2 aggregate + fused layer-3 matvec: gather Gh rows -> relu F rows
// (LDS) -> block 32x32 matvec -> Gh3 (fp16)
__global__ void k_agg2mv(const uint2* __restrict__ rs2, const int* __restrict__ ss,
                         const half8* __restrict__ G8, const float* __restrict__ dinv,
                         const float* __restrict__ b, const float* __restrict__ Wmid,
                         _Float16* __restrict__ Gh3, int N) {
    __shared__ float sW[1024];
    __shared__ float sF[8][33];
    __shared__ float sdv[8];
    int t = threadIdx.x;
    #pragma unroll
    for (int r = 0; r < 4; ++r) sW[r * 256 + t] = Wmid[r * 256 + t];
    int tg = blockIdx.x * blockDim.x + t;
    int g = tg >> 5;
    int lane = t & 31, sub = lane >> 2, fl = lane & 3;
    int grp = t >> 5;
    bool act = (g < N);
    float acc[8];
    #pragma unroll
    for (int j = 0; j < 8; ++j) acc[j] = 0.f;
    if (act) {
        uint2 r = rs2[g];
        int beg = (int)r.x, end = (int)(r.x + r.y);
        if (sub == 0) {
            half8 v = G8[(long long)g * 4 + fl];
            #pragma unroll
            for (int j = 0; j < 8; ++j) acc[j] = (float)v[j];
        }
        int e = beg + sub;
        for (; e + 8 < end; e += 16) {
            int s0 = ss[e], s1 = ss[e + 8];
            half8 v0 = G8[(long long)s0 * 4 + fl];
            half8 v1 = G8[(long long)s1 * 4 + fl];
            #pragma unroll
            for (int j = 0; j < 8; ++j) acc[j] += (float)v0[j] + (float)v1[j];
        }
        for (; e < end; e += 8) {
            half8 v0 = G8[(long long)ss[e] * 4 + fl];
            #pragma unroll
            for (int j = 0; j < 8; ++j) acc[j] += (float)v0[j];
        }
    }
    #pragma unroll
    for (int j = 0; j < 8; ++j) {
        acc[j] += __shfl_xor(acc[j], 4);
        acc[j] += __shfl_xor(acc[j], 8);
        acc[j] += __shfl_xor(acc[j], 16);
    }
    if (act && sub == 0) {
        float d = dinv[g];
        if (fl == 0) sdv[grp] = d;
        #pragma unroll
        for (int j = 0; j < 8; ++j) {
            float v = d * acc[j] + b[fl * 8 + j];
            sF[grp][fl * 8 + j] = v > 0.f ? v : 0.f;
        }
    }
    __syncthreads();
    // block matvec: node grp, output feature lane
    if (act) {
        float s = 0.f;
        #pragma unroll
        for (int k = 0; k < 32; ++k) s += sF[grp][k] * sW[k * 32 + lane];
        Gh3[(long long)g * 32 + lane] = (_Float16)(s * sdv[grp]);
    }
}

// layer-3 aggregate + fused W_out dot: writes only sa[i]
__global__ void k_agg3(const uint2* __restrict__ rs2, const int* __restrict__ ss,
                       const half8* __restrict__ G8, const float* __restrict__ dinv,
                       const float* __restrict__ b, const float* __restrict__ Wout,
                       float* __restrict__ sa, int N) {
    int t = blockIdx.x * blockDim.x + threadIdx.x;
    int g = t >> 5;
    if (g >= N) return;
    int lane = t & 31, sub = lane >> 2, fl = lane & 3;
    uint2 r = rs2[g];
    int beg = (int)r.x, end = (int)(r.x + r.y);
    float acc[8];
    #pragma unroll
    for (int j = 0; j < 8; ++j) acc[j] = 0.f;
    if (sub == 0) {
        half8 v = G8[(long long)g * 4 + fl];
        #pragma unroll
        for (int j = 0; j < 8; ++j) acc[j] = (float)v[j];
    }
    int e = beg + sub;
    for (; e + 8 < end; e += 16) {
        int s0 = ss[e], s1 = ss[e + 8];
        half8 v0 = G8[(long long)s0 * 4 + fl];
        half8 v1 = G8[(long long)s1 * 4 + fl];
        #pragma unroll
        for (int j = 0; j < 8; ++j) acc[j] += (float)v0[j] + (float)v1[j];
    }
    for (; e < end; e += 8) {
        half8 v0 = G8[(long long)ss[e] * 4 + fl];
        #pragma unroll
        for (int j = 0; j < 8; ++j) acc[j] += (float)v0[j];
    }
    #pragma unroll
    for (int j = 0; j < 8; ++j) {
        acc[j] += __shfl_xor(acc[j], 4);
        acc[j] += __shfl_xor(acc[j], 8);
        acc[j] += __shfl_xor(acc[j], 16);
    }
    if (sub == 0) {
        float d = dinv[g];
        float p = 0.f;
        #pragma unroll
        for (int j = 0; j < 8; ++j) {
            float v = d * acc[j] + b[fl * 8 + j];
            v = v > 0.f ? v : 0.f;
            p += v * Wout[fl * 8 + j];
        }
        p += __shfl_xor(p, 1, 32);
        p += __shfl_xor(p, 2, 32);
        if (fl == 0) sa[g] = p * d;
    }
}

// layer 4: scalar gather-reduce + sigmoid, fused
__global__ void k_final_agg(const uint2* __restrict__ rs2, const int* __restrict__ ss,
                            const float* __restrict__ sa, const float* __restrict__ dinv,
                            const float* __restrict__ bout, float* __restrict__ out, int N) {
    int t = blockIdx.x * blockDim.x + threadIdx.x;
    int i = t >> 5, l = t & 31;
    if (i >= N) return;
    uint2 r = rs2[i];
    int beg = (int)r.x, end = (int)(r.x + r.y);
    float s = 0.f;
    for (int e = beg + l; e < end; e += 32) s += sa[ss[e]];
    #pragma unroll
    for (int m = 16; m; m >>= 1) s += __shfl_xor(s, m, 32);
    if (l == 0) {
        float z = dinv[i] * (s + sa[i]) + bout[0];
        out[i] = 1.0f / (1.0f + expf(-z));
    }
}

extern "C" void kernel_launch(void* const* d_in, const int* in_sizes, int n_in,
                              void* d_out, int out_size, void* d_ws, size_t ws_size,
                              hipStream_t stream) {
    const float* x    = (const float*)d_in[0];
    const int*   ei   = (const int*)  d_in[1];
    const float* Win  = (const float*)d_in[2];
    const float* bin  = (const float*)d_in[3];
    const float* Wmid = (const float*)d_in[4];
    const float* bmid = (const float*)d_in[5];
    const float* Wout = (const float*)d_in[6];
    const float* bout = (const float*)d_in[7];
    float* out = (float*)d_out;

    int N = in_sizes[0];
    int E = in_sizes[1] / 2;
    const int* src = ei;
    const int* dst = ei + E;

    int NB = (N + 127) >> 7;                       // 782 buckets of 128 nodes
    int chunk = (E + NBLK - 1) / NBLK;             // 12500

    // workspace layout (all regions disjoint; ~47MB)
    int* cursor = (int*)d_ws;                      // 1024
    uint2* rs2  = (uint2*)(cursor + 1024);         // N+8
    int* ss     = (int*)(rs2 + N + 8);             // NB*CAP
    float* dinv = (float*)(ss + (size_t)NB * CAP); // N
    float* sa   = dinv + N;                        // N
    _Float16* Gh  = (_Float16*)(sa + N);           // 32N fp16
    _Float16* Gh3 = Gh + 32 * (size_t)N;           // 32N fp16
    int* bkt    = (int*)(Gh3 + 32 * (size_t)N);    // NB*CAP

    int NT   = N * 32;
    int gN32 = (NT + BLK - 1) / BLK;

    // CSR build: init cursors -> LDS multisplit place -> per-bucket sort
    k_initcur<<<(NB + BLK - 1) / BLK, BLK, 0, stream>>>(cursor, NB);
    k_place<<<NBLK, PBLK, 0, stream>>>(src, dst, cursor, bkt, E, chunk);
    k_build<<<NB, BLK, 0, stream>>>(cursor, bkt, x, rs2, ss, dinv, sa, N);

    // layer 1 (+ fused layer-2 matvec) -> Gh
    k_l1aggG<<<gN32, BLK, 0, stream>>>(rs2, ss, sa, dinv, Win, bin, Wmid, Gh, N);

    // layer 2 aggregate (+ fused layer-3 matvec) -> Gh3
    k_agg2mv<<<gN32, BLK, 0, stream>>>(rs2, ss, (const half8*)Gh, dinv, bmid,
                                       Wmid, Gh3, N);

    // layer 3 aggregate (+ fused W_out dot) -> sa
    k_agg3<<<gN32, BLK, 0, stream>>>(rs2, ss, (const half8*)Gh3, dinv, bmid,
                                     Wout, sa, N);

    // layer 4: scalar aggregate + sigmoid
    k_final_agg<<<gN32, BLK, 0, stream>>>(rs2, ss, sa, dinv, bout, out, N);
}

// Round 12
// 249.631 us; speedup vs baseline: 1.0645x; 1.0645x over previous
//
#include <hip/hip_runtime.h>
#include <math.h>

// GCN 4-layer, N=100k, E=3.2M. Round 12:
//  - Revert r11's 32-class sort (FETCH unchanged 99MB, build got pricier):
//    back to r10's 8-class / 1024-bin k_build, now at 512 threads.
//  - Wide aggs: gather loop unrolled 2 -> 4 outstanding loads (miss-latency
//    bound at ~40% L2 miss; VGPR=20 has headroom).
// Identities: norm factorizes (dinv pre/post scale); matmul commutes with
// segment-sum, so layers 1/4 aggregate scalars.

#define BLK 256
#define PBLK 1024         // k_place threads
#define BBLK 512          // k_build threads
#define NBLK 256          // edge-pass blocks
#define MAXCHUNK 12544    // >= ceil(E/NBLK)=12500
#define CAP 5120          // per-bucket segment capacity (mean 4096, +16 sigma)

typedef _Float16 half8 __attribute__((ext_vector_type(8)));

// ---- CSR build ----------------------------------------------------------

__global__ void k_initcur(int* __restrict__ cursor, int NB) {
    int b = blockIdx.x * blockDim.x + threadIdx.x;
    if (b < NB) cursor[b] = b * CAP;
}

// per-block LDS multisplit + coalesced flush into segmented bkt regions
__global__ void __launch_bounds__(PBLK) k_place(
        const int* __restrict__ src, const int* __restrict__ dst,
        int* __restrict__ cursor, int* __restrict__ bkt, int E, int chunk) {
    __shared__ int hist[788];          // counts, then wbase after reservation
    __shared__ int lofs[788];
    __shared__ int lcur[788];
    __shared__ int tmp[PBLK];
    __shared__ int stage[MAXCHUNK];
    int t = threadIdx.x;
    int b0 = blockIdx.x * chunk;
    int b1 = min(E, b0 + chunk);
    int n = b1 - b0;
    if (t < 788) hist[t] = 0;
    __syncthreads();
    for (int k = b0 + t; k < b1; k += PBLK) atomicAdd(&hist[dst[k] >> 7], 1);
    __syncthreads();
    int v = (t < 788) ? hist[t] : 0;
    tmp[t] = v;
    __syncthreads();
    for (int o = 1; o < PBLK; o <<= 1) {
        int a = (t >= o) ? tmp[t - o] : 0;
        __syncthreads();
        tmp[t] += a;
        __syncthreads();
    }
    int ex = tmp[t] - v;
    if (t < 788) { lofs[t] = ex; lcur[t] = ex; }
    __syncthreads();
    if (t < 782) {
        int c = hist[t];
        hist[t] = c ? atomicAdd(&cursor[t], c) : 0;   // segmented reservation
    }
    __syncthreads();
    for (int k = b0 + t; k < b1; k += PBLK) {
        int d = dst[k], s = src[k];
        int b = d >> 7;
        int p = atomicAdd(&lcur[b], 1);
        stage[p] = s | ((d & 127) << 17);
    }
    __syncthreads();
    for (int k = t; k < n; k += PBLK) {
        int lo = 0, hi = 781;
        while (lo < hi) {
            int mid = (lo + hi + 1) >> 1;
            if (lofs[mid] <= k) lo = mid; else hi = mid - 1;
        }
        int pos = hist[lo] + (k - lofs[lo]);
        if (pos < (lo + 1) * CAP) bkt[pos] = stage[k];   // clamp (never hits)
    }
}

// block per bucket -> 1024-bin (node, src>>14) hist + in-place scan, LDS
// scatter, linear flush; writes rs2 (beg,len), dinv, sa
__global__ void __launch_bounds__(BBLK) k_build(
        const int* __restrict__ cursor, const int* __restrict__ bkt,
        const float* __restrict__ x,
        uint2* __restrict__ rs2, int* __restrict__ ss,
        float* __restrict__ dinv, float* __restrict__ sa, int N) {
    __shared__ int cnt[1024], lofs[1024], lcur[1024];
    __shared__ int tmp[BBLK];
    __shared__ int stg[CAP];
    int b = blockIdx.x, t = threadIdx.x;
    int node_base = b << 7;
    int gb = b * CAP;
    int sz = min(cursor[b] - gb, CAP);
    for (int i = t; i < 1024; i += BBLK) cnt[i] = 0;
    __syncthreads();
    const int* q = bkt + gb;
    for (int k = t; k < sz; k += BBLK) {
        int v = q[k];
        int bin = (((v >> 17) & 127) << 3) | ((v & 0x1FFFF) >> 14);
        atomicAdd(&cnt[bin], 1);
    }
    __syncthreads();
    // in-place scan of 1024 bins, 2 per thread
    int vals[2];
    int sum = 0;
    int i0 = t << 1;
    #pragma unroll
    for (int r = 0; r < 2; ++r) { vals[r] = cnt[i0 + r]; sum += vals[r]; }
    tmp[t] = sum;
    __syncthreads();
    for (int o = 1; o < BBLK; o <<= 1) {
        int a = (t >= o) ? tmp[t - o] : 0;
        __syncthreads();
        tmp[t] += a;
        __syncthreads();
    }
    int run = tmp[t] - sum;
    #pragma unroll
    for (int r = 0; r < 2; ++r) {
        int c = vals[r];
        lofs[i0 + r] = run;
        lcur[i0 + r] = run;
        run += c;
    }
    __syncthreads();
    if (t < 128) {
        int i = node_base + t;
        if (i < N) {
            int beg = lofs[t << 3];
            int end = (t < 127) ? lofs[(t + 1) << 3] : sz;
            int len = end - beg;
            rs2[i] = make_uint2((unsigned)(gb + beg), (unsigned)len);
            float d = rsqrtf((float)len + 1.0f);
            dinv[i] = d;
            sa[i] = x[i] * d;
        }
    }
    __syncthreads();
    for (int k = t; k < sz; k += BBLK) {
        int v = q[k];
        int bin = (((v >> 17) & 127) << 3) | ((v & 0x1FFFF) >> 14);
        int pos = atomicAdd(&lcur[bin], 1);
        stg[pos] = v & 0x1FFFF;
    }
    __syncthreads();
    for (int k = t; k < sz; k += BBLK) ss[gb + k] = stg[k];
}

// ---- layers -------------------------------------------------------------

// layer 1 + fused layer-2 matvec: scalar gather -> F1 (lane=feature) ->
// Gh[i,l] = dinv_i * sum_k F1_k * Wmid[k][l], via 32 shuffles
__global__ void k_l1aggG(const uint2* __restrict__ rs2, const int* __restrict__ ss,
                         const float* __restrict__ sa, const float* __restrict__ dinv,
                         const float* __restrict__ Win, const float* __restrict__ bin,
                         const float* __restrict__ Wmid, _Float16* __restrict__ Gh, int N) {
    int t = blockIdx.x * blockDim.x + threadIdx.x;
    int i = t >> 5, l = t & 31;
    if (i >= N) return;
    float wcol[32];
    #pragma unroll
    for (int k = 0; k < 32; ++k) wcol[k] = Wmid[k * 32 + l];
    uint2 r = rs2[i];
    int beg = (int)r.x, end = (int)(r.x + r.y);
    float s = 0.f;
    for (int e = beg + l; e < end; e += 32) s += sa[ss[e]];
    #pragma unroll
    for (int m = 16; m; m >>= 1) s += __shfl_xor(s, m, 32);
    float d = dinv[i];
    float h = d * (s + sa[i]);
    float F = h * Win[l] + bin[l];
    F = F > 0.f ? F : 0.f;
    float g = 0.f;
    #pragma unroll
    for (int k = 0; k < 32; ++k) g += __shfl(F, k, 32) * wcol[k];
    Gh[t] = (_Float16)(g * d);
}

// layer-2 aggregate + fused layer-3 matvec: gather Gh rows -> relu F rows
// (LDS) -> block 32x32 matvec -> Gh3 (fp16). 4-deep gather unroll.
__global__ void k_agg2mv(const uint2* __restrict__ rs2, const int* __restrict__ ss,
                         const half8* __restrict__ G8, const float* __restrict__ dinv,
                         const float* __restrict__ b, const float* __restrict__ Wmid,
                         _Float16* __restrict__ Gh3, int N) {
    __shared__ float sW[1024];
    __shared__ float sF[8][33];
    __shared__ float sdv[8];
    int t = threadIdx.x;
    #pragma unroll
    for (int r = 0; r < 4; ++r) sW[r * 256 + t] = Wmid[r * 256 + t];
    int tg = blockIdx.x * blockDim.x + t;
    int g = tg >> 5;
    int lane = t & 31, sub = lane >> 2, fl = lane & 3;
    int grp = t >> 5;
    bool act = (g < N);
    float acc[8];
    #pragma unroll
    for (int j = 0; j < 8; ++j) acc[j] = 0.f;
    if (act) {
        uint2 r = rs2[g];
        int beg = (int)r.x, end = (int)(r.x + r.y);
        if (sub == 0) {
            half8 v = G8[(long long)g * 4 + fl];
            #pragma unroll
            for (int j = 0; j < 8; ++j) acc[j] = (float)v[j];
        }
        int e = beg + sub;
        for (; e + 24 < end; e += 32) {
            int s0 = ss[e], s1 = ss[e + 8], s2 = ss[e + 16], s3 = ss[e + 24];
            half8 v0 = G8[(long long)s0 * 4 + fl];
            half8 v1 = G8[(long long)s1 * 4 + fl];
            half8 v2 = G8[(long long)s2 * 4 + fl];
            half8 v3 = G8[(long long)s3 * 4 + fl];
            #pragma unroll
            for (int j = 0; j < 8; ++j)
                acc[j] += ((float)v0[j] + (float)v1[j]) + ((float)v2[j] + (float)v3[j]);
        }
        for (; e < end; e += 8) {
            half8 v0 = G8[(long long)ss[e] * 4 + fl];
            #pragma unroll
            for (int j = 0; j < 8; ++j) acc[j] += (float)v0[j];
        }
    }
    #pragma unroll
    for (int j = 0; j < 8; ++j) {
        acc[j] += __shfl_xor(acc[j], 4);
        acc[j] += __shfl_xor(acc[j], 8);
        acc[j] += __shfl_xor(acc[j], 16);
    }
    if (act && sub == 0) {
        float d = dinv[g];
        if (fl == 0) sdv[grp] = d;
        #pragma unroll
        for (int j = 0; j < 8; ++j) {
            float v = d * acc[j] + b[fl * 8 + j];
            sF[grp][fl * 8 + j] = v > 0.f ? v : 0.f;
        }
    }
    __syncthreads();
    // block matvec: node grp, output feature lane
    if (act) {
        float s = 0.f;
        #pragma unroll
        for (int k = 0; k < 32; ++k) s += sF[grp][k] * sW[k * 32 + lane];
        Gh3[(long long)g * 32 + lane] = (_Float16)(s * sdv[grp]);
    }
}

// layer-3 aggregate + fused W_out dot: writes only sa[i]. 4-deep unroll.
__global__ void k_agg3(const uint2* __restrict__ rs2, const int* __restrict__ ss,
                       const half8* __restrict__ G8, const float* __restrict__ dinv,
                       const float* __restrict__ b, const float* __restrict__ Wout,
                       float* __restrict__ sa, int N) {
    int t = blockIdx.x * blockDim.x + threadIdx.x;
    int g = t >> 5;
    if (g >= N) return;
    int lane = t & 31, sub = lane >> 2, fl = lane & 3;
    uint2 r = rs2[g];
    int beg = (int)r.x, end = (int)(r.x + r.y);
    float acc[8];
    #pragma unroll
    for (int j = 0; j < 8; ++j) acc[j] = 0.f;
    if (sub == 0) {
        half8 v = G8[(long long)g * 4 + fl];
        #pragma unroll
        for (int j = 0; j < 8; ++j) acc[j] = (float)v[j];
    }
    int e = beg + sub;
    for (; e + 24 < end; e += 32) {
        int s0 = ss[e], s1 = ss[e + 8], s2 = ss[e + 16], s3 = ss[e + 24];
        half8 v0 = G8[(long long)s0 * 4 + fl];
        half8 v1 = G8[(long long)s1 * 4 + fl];
        half8 v2 = G8[(long long)s2 * 4 + fl];
        half8 v3 = G8[(long long)s3 * 4 + fl];
        #pragma unroll
        for (int j = 0; j < 8; ++j)
            acc[j] += ((float)v0[j] + (float)v1[j]) + ((float)v2[j] + (float)v3[j]);
    }
    for (; e < end; e += 8) {
        half8 v0 = G8[(long long)ss[e] * 4 + fl];
        #pragma unroll
        for (int j = 0; j < 8; ++j) acc[j] += (float)v0[j];
    }
    #pragma unroll
    for (int j = 0; j < 8; ++j) {
        acc[j] += __shfl_xor(acc[j], 4);
        acc[j] += __shfl_xor(acc[j], 8);
        acc[j] += __shfl_xor(acc[j], 16);
    }
    if (sub == 0) {
        float d = dinv[g];
        float p = 0.f;
        #pragma unroll
        for (int j = 0; j < 8; ++j) {
            float v = d * acc[j] + b[fl * 8 + j];
            v = v > 0.f ? v : 0.f;
            p += v * Wout[fl * 8 + j];
        }
        p += __shfl_xor(p, 1, 32);
        p += __shfl_xor(p, 2, 32);
        if (fl == 0) sa[g] = p * d;
    }
}

// layer 4: scalar gather-reduce + sigmoid, fused
__global__ void k_final_agg(const uint2* __restrict__ rs2, const int* __restrict__ ss,
                            const float* __restrict__ sa, const float* __restrict__ dinv,
                            const float* __restrict__ bout, float* __restrict__ out, int N) {
    int t = blockIdx.x * blockDim.x + threadIdx.x;
    int i = t >> 5, l = t & 31;
    if (i >= N) return;
    uint2 r = rs2[i];
    int beg = (int)r.x, end = (int)(r.x + r.y);
    float s = 0.f;
    for (int e = beg + l; e < end; e += 32) s += sa[ss[e]];
    #pragma unroll
    for (int m = 16; m; m >>= 1) s += __shfl_xor(s, m, 32);
    if (l == 0) {
        float z = dinv[i] * (s + sa[i]) + bout[0];
        out[i] = 1.0f / (1.0f + expf(-z));
    }
}

extern "C" void kernel_launch(void* const* d_in, const int* in_sizes, int n_in,
                              void* d_out, int out_size, void* d_ws, size_t ws_size,
                              hipStream_t stream) {
    const float* x    = (const float*)d_in[0];
    const int*   ei   = (const int*)  d_in[1];
    const float* Win  = (const float*)d_in[2];
    const float* bin  = (const float*)d_in[3];
    const float* Wmid = (const float*)d_in[4];
    const float* bmid = (const float*)d_in[5];
    const float* Wout = (const float*)d_in[6];
    const float* bout = (const float*)d_in[7];
    float* out = (float*)d_out;

    int N = in_sizes[0];
    int E = in_sizes[1] / 2;
    const int* src = ei;
    const int* dst = ei + E;

    int NB = (N + 127) >> 7;                       // 782 buckets of 128 nodes
    int chunk = (E + NBLK - 1) / NBLK;             // 12500

    // workspace layout (all regions disjoint; ~47MB)
    int* cursor = (int*)d_ws;                      // 1024
    uint2* rs2  = (uint2*)(cursor + 1024);         // N+8
    int* ss     = (int*)(rs2 + N + 8);             // NB*CAP
    float* dinv = (float*)(ss + (size_t)NB * CAP); // N
    float* sa   = dinv + N;                        // N
    _Float16* Gh  = (_Float16*)(sa + N);           // 32N fp16
    _Float16* Gh3 = Gh + 32 * (size_t)N;           // 32N fp16
    int* bkt    = (int*)(Gh3 + 32 * (size_t)N);    // NB*CAP

    int NT   = N * 32;
    int gN32 = (NT + BLK - 1) / BLK;

    // CSR build: init cursors -> LDS multisplit place -> per-bucket sort
    k_initcur<<<(NB + BLK - 1) / BLK, BLK, 0, stream>>>(cursor, NB);
    k_place<<<NBLK, PBLK, 0, stream>>>(src, dst, cursor, bkt, E, chunk);
    k_build<<<NB, BBLK, 0, stream>>>(cursor, bkt, x, rs2, ss, dinv, sa, N);

    // layer 1 (+ fused layer-2 matvec) -> Gh
    k_l1aggG<<<gN32, BLK, 0, stream>>>(rs2, ss, sa, dinv, Win, bin, Wmid, Gh, N);

    // layer 2 aggregate (+ fused layer-3 matvec) -> Gh3
    k_agg2mv<<<gN32, BLK, 0, stream>>>(rs2, ss, (const half8*)Gh, dinv, bmid,
                                       Wmid, Gh3, N);

    // layer 3 aggregate (+ fused W_out dot) -> sa
    k_agg3<<<gN32, BLK, 0, stream>>>(rs2, ss, (const half8*)Gh3, dinv, bmid,
                                     Wout, sa, N);

    // layer 4: scalar aggregate + sigmoid
    k_final_agg<<<gN32, BLK, 0, stream>>>(rs2, ss, sa, dinv, bout, out, N);
}